// Round 1
// baseline (164.325 us; speedup 1.0000x reference)
//
#include <hip/hip_runtime.h>

#define RNN 2048
#define AH  512
#define BB  128
#define LL  196

// ---------------- k1: att_h[b][a] = sum_k h[b][k]*w[a][k] + bias[a] ----------------
// grid (4 a-chunks, 32 b-groups), 512 threads. 4 h-rows staged in LDS (32 KB).
__global__ __launch_bounds__(512) void k1_atth(const float* __restrict__ h,
                                               const float* __restrict__ w,
                                               const float* __restrict__ bias,
                                               float* __restrict__ att_h) {
    __shared__ float hs[4][RNN];
    const int tid = threadIdx.x;
    const int bg  = blockIdx.y;   // group of 4 batch rows
    const int ac  = blockIdx.x;   // chunk of 128 attention-hidden cols

    // cooperative, coalesced load of 4 h rows (8192 floats)
    #pragma unroll
    for (int i = 0; i < 16; ++i) {
        int idx = tid + i * 512;
        int bl = idx >> 11, k = idx & 2047;
        hs[bl][k] = h[(bg * 4 + bl) * RNN + k];
    }
    __syncthreads();

    const int a_local = tid & 127, b_local = tid >> 7;
    const int a = ac * 128 + a_local;
    const float4* wr = reinterpret_cast<const float4*>(w + (size_t)a * RNN);
    const float4* hr = reinterpret_cast<const float4*>(hs[b_local]);
    float acc = 0.f;
    #pragma unroll 4
    for (int k4 = 0; k4 < RNN / 4; ++k4) {
        float4 wv = wr[k4];
        float4 hv = hr[k4];   // broadcast within the 128 a-threads: conflict-free
        acc += wv.x * hv.x + wv.y * hv.y + wv.z * hv.z + wv.w * hv.w;
    }
    att_h[(bg * 4 + b_local) * AH + a] = acc + bias[a];
}

// ---------------- k2: scores[b][l] = sum_a tanh(iaf+att_h)*alpha_w + alpha_b -------
// one wave per (b,l); 4 waves per block.
__global__ __launch_bounds__(256) void k2_scores(const float* __restrict__ iaf,
                                                 const float* __restrict__ att_h,
                                                 const float* __restrict__ aw,
                                                 const float* __restrict__ ab,
                                                 float* __restrict__ scores) {
    const int wid  = blockIdx.x * 4 + (threadIdx.x >> 6);
    const int lane = threadIdx.x & 63;
    if (wid >= BB * LL) return;
    const int b = wid / LL, l = wid - b * LL;

    const float4* ir = reinterpret_cast<const float4*>(iaf + (size_t)(b * LL + l) * AH);
    const float4* hr = reinterpret_cast<const float4*>(att_h + (size_t)b * AH);
    const float4* ar = reinterpret_cast<const float4*>(aw);

    float s = 0.f;
    #pragma unroll
    for (int c = 0; c < 2; ++c) {
        int idx = lane + c * 64;        // 64 lanes x 16B = 1 KB contiguous
        float4 iv = ir[idx];
        float4 hv = hr[idx];
        float4 av = ar[idx];
        s += tanhf(iv.x + hv.x) * av.x
           + tanhf(iv.y + hv.y) * av.y
           + tanhf(iv.z + hv.z) * av.z
           + tanhf(iv.w + hv.w) * av.w;
    }
    #pragma unroll
    for (int off = 32; off; off >>= 1) s += __shfl_xor(s, off);
    if (lane == 0) scores[b * LL + l] = s + ab[0];
}

// ---------------- k3: weight[b][:] = softmax(scores[b][:]) over L ------------------
__global__ __launch_bounds__(256) void k3_softmax(const float* __restrict__ scores,
                                                  float* __restrict__ weight) {
    const int b = blockIdx.x;
    const int t = threadIdx.x;
    __shared__ float red[4];
    float v = (t < LL) ? scores[b * LL + t] : -1e30f;

    float m = v;
    #pragma unroll
    for (int off = 32; off; off >>= 1) m = fmaxf(m, __shfl_xor(m, off));
    if ((t & 63) == 0) red[t >> 6] = m;
    __syncthreads();
    m = fmaxf(fmaxf(red[0], red[1]), fmaxf(red[2], red[3]));
    __syncthreads();

    float e = (t < LL) ? __expf(v - m) : 0.f;
    float s = e;
    #pragma unroll
    for (int off = 32; off; off >>= 1) s += __shfl_xor(s, off);
    if ((t & 63) == 0) red[t >> 6] = s;
    __syncthreads();
    s = red[0] + red[1] + red[2] + red[3];

    if (t < LL) weight[b * LL + t] = e / s;
}

// ---------------- k4: out[b][d] = sum_l weight[b][l] * att_feats[b][l][d] ----------
// grid (4 d-chunks of 512, 128 b). 128 threads, float4 per thread.
__global__ __launch_bounds__(128) void k4_out(const float* __restrict__ af,
                                              const float* __restrict__ weight,
                                              float* __restrict__ out) {
    const int b  = blockIdx.y;
    const int d0 = blockIdx.x * 512 + threadIdx.x * 4;

    __shared__ float wsm[LL];
    for (int i = threadIdx.x; i < LL; i += 128) wsm[i] = weight[b * LL + i];
    __syncthreads();

    const float* base = af + (size_t)b * LL * RNN + d0;
    float4 acc = {0.f, 0.f, 0.f, 0.f};
    #pragma unroll 4
    for (int l = 0; l < LL; ++l) {
        float wl = wsm[l];
        float4 v = *reinterpret_cast<const float4*>(base + (size_t)l * RNN);
        acc.x += wl * v.x; acc.y += wl * v.y; acc.z += wl * v.z; acc.w += wl * v.w;
    }
    *reinterpret_cast<float4*>(out + (size_t)b * RNN + d0) = acc;
}

extern "C" void kernel_launch(void* const* d_in, const int* in_sizes, int n_in,
                              void* d_out, int out_size, void* d_ws, size_t ws_size,
                              hipStream_t stream) {
    const float* h    = (const float*)d_in[0];   // [128,2048]
    const float* af   = (const float*)d_in[1];   // [128,196,2048]
    const float* iaf  = (const float*)d_in[2];   // [128,196,512]
    const float* w    = (const float*)d_in[3];   // [512,2048]
    const float* bias = (const float*)d_in[4];   // [512]
    const float* aw   = (const float*)d_in[5];   // [1,512]
    const float* ab   = (const float*)d_in[6];   // [1]
    float* out = (float*)d_out;

    float* ws_f    = (float*)d_ws;
    float* att_h   = ws_f;                       // 128*512
    float* scores  = ws_f + BB * AH;             // 128*196
    float* weight  = scores + BB * LL;           // 128*196

    k1_atth<<<dim3(4, 32), 512, 0, stream>>>(h, w, bias, att_h);

    int nwl = BB * LL;                           // 25088 waves
    k2_scores<<<(nwl + 3) / 4, 256, 0, stream>>>(iaf, att_h, aw, ab, scores);

    k3_softmax<<<BB, 256, 0, stream>>>(scores, weight);

    k4_out<<<dim3(4, BB), 128, 0, stream>>>(af, weight, out);
}

// Round 2
// 65.966 us; speedup vs baseline: 2.4910x; 2.4910x over previous
//
#include <hip/hip_runtime.h>

#define RNN 2048
#define AH  512
#define BB  128
#define LL  196

// ---------------- k1: att_h[b][a] = sum_k h[b][k]*w[a][k] + bias[a] ----------------
// Lanes run along K (coalesced w reads), shuffle-reduce at the end.
// Block: 256 threads = 4 waves; handles 4 b-rows x 32 a-cols.
// Wave wv owns a-cols [a0 + wv*8, +8) for all 4 b. Grid (16 a-groups, 32 b-groups).
__global__ __launch_bounds__(256) void k1_atth(const float* __restrict__ h,
                                               const float* __restrict__ w,
                                               const float* __restrict__ bias,
                                               float* __restrict__ att_h) {
    __shared__ float hs[4 * RNN];                 // 32 KB: 4 h rows
    const int tid  = threadIdx.x;
    const int wv   = tid >> 6, lane = tid & 63;
    const int b0   = blockIdx.y * 4;
    const int a0   = blockIdx.x * 32 + wv * 8;

    // cooperative coalesced load of 4 h rows (8192 floats = 2048 float4)
    const float4* hg  = reinterpret_cast<const float4*>(h + (size_t)b0 * RNN);
    float4*       hs4 = reinterpret_cast<float4*>(hs);
    #pragma unroll
    for (int i = 0; i < 8; ++i) hs4[tid + i * 256] = hg[tid + i * 256];
    __syncthreads();

    float acc[8][4];
    #pragma unroll
    for (int ai = 0; ai < 8; ++ai)
        #pragma unroll
        for (int bl = 0; bl < 4; ++bl) acc[ai][bl] = 0.f;

    const float4* w4 = reinterpret_cast<const float4*>(w);
    #pragma unroll 1
    for (int i = 0; i < 8; ++i) {                 // k-chunks of 256 floats
        const int k4 = i * 64 + lane;             // float4 index in row (512/row)
        float4 hv[4];
        #pragma unroll
        for (int bl = 0; bl < 4; ++bl) hv[bl] = hs4[bl * 512 + k4];
        #pragma unroll
        for (int ai = 0; ai < 8; ++ai) {
            float4 wvv = w4[(size_t)(a0 + ai) * 512 + k4];  // 64 lanes x 16B contiguous
            #pragma unroll
            for (int bl = 0; bl < 4; ++bl)
                acc[ai][bl] += wvv.x * hv[bl].x + wvv.y * hv[bl].y
                             + wvv.z * hv[bl].z + wvv.w * hv[bl].w;
        }
    }

    // full butterfly reduce (every lane ends with the sum)
    #pragma unroll
    for (int off = 32; off; off >>= 1)
        #pragma unroll
        for (int ai = 0; ai < 8; ++ai)
            #pragma unroll
            for (int bl = 0; bl < 4; ++bl)
                acc[ai][bl] += __shfl_xor(acc[ai][bl], off);

    if (lane == 0) {
        #pragma unroll
        for (int ai = 0; ai < 8; ++ai) {
            const float ba = bias[a0 + ai];
            #pragma unroll
            for (int bl = 0; bl < 4; ++bl)
                att_h[(b0 + bl) * AH + a0 + ai] = acc[ai][bl] + ba;
        }
    }
}

// ---------------- k2: scores[b][l] = sum_a tanh(iaf+att_h)*alpha_w + alpha_b -------
// one wave per (b,l); 4 waves per block.
__global__ __launch_bounds__(256) void k2_scores(const float* __restrict__ iaf,
                                                 const float* __restrict__ att_h,
                                                 const float* __restrict__ aw,
                                                 const float* __restrict__ ab,
                                                 float* __restrict__ scores) {
    const int wid  = blockIdx.x * 4 + (threadIdx.x >> 6);
    const int lane = threadIdx.x & 63;
    if (wid >= BB * LL) return;
    const int b = wid / LL, l = wid - b * LL;

    const float4* ir = reinterpret_cast<const float4*>(iaf + (size_t)(b * LL + l) * AH);
    const float4* hr = reinterpret_cast<const float4*>(att_h + (size_t)b * AH);
    const float4* ar = reinterpret_cast<const float4*>(aw);

    float s = 0.f;
    #pragma unroll
    for (int c = 0; c < 2; ++c) {
        int idx = lane + c * 64;        // 64 lanes x 16B = 1 KB contiguous
        float4 iv = ir[idx];
        float4 hv = hr[idx];
        float4 av = ar[idx];
        s += tanhf(iv.x + hv.x) * av.x
           + tanhf(iv.y + hv.y) * av.y
           + tanhf(iv.z + hv.z) * av.z
           + tanhf(iv.w + hv.w) * av.w;
    }
    #pragma unroll
    for (int off = 32; off; off >>= 1) s += __shfl_xor(s, off);
    if (lane == 0) scores[b * LL + l] = s + ab[0];
}

// ---------------- k3: weight[b][:] = softmax(scores[b][:]) over L ------------------
__global__ __launch_bounds__(256) void k3_softmax(const float* __restrict__ scores,
                                                  float* __restrict__ weight) {
    const int b = blockIdx.x;
    const int t = threadIdx.x;
    __shared__ float red[4];
    float v = (t < LL) ? scores[b * LL + t] : -1e30f;

    float m = v;
    #pragma unroll
    for (int off = 32; off; off >>= 1) m = fmaxf(m, __shfl_xor(m, off));
    if ((t & 63) == 0) red[t >> 6] = m;
    __syncthreads();
    m = fmaxf(fmaxf(red[0], red[1]), fmaxf(red[2], red[3]));
    __syncthreads();

    float e = (t < LL) ? __expf(v - m) : 0.f;
    float s = e;
    #pragma unroll
    for (int off = 32; off; off >>= 1) s += __shfl_xor(s, off);
    if ((t & 63) == 0) red[t >> 6] = s;
    __syncthreads();
    s = red[0] + red[1] + red[2] + red[3];

    if (t < LL) weight[b * LL + t] = e / s;
}

// ---------------- k4: out[b][d] = sum_l weight[b][l] * att_feats[b][l][d] ----------
// grid (4 d-chunks of 512, 128 b). 128 threads, float4 per thread.
__global__ __launch_bounds__(128) void k4_out(const float* __restrict__ af,
                                              const float* __restrict__ weight,
                                              float* __restrict__ out) {
    const int b  = blockIdx.y;
    const int d0 = blockIdx.x * 512 + threadIdx.x * 4;

    __shared__ float wsm[LL];
    for (int i = threadIdx.x; i < LL; i += 128) wsm[i] = weight[b * LL + i];
    __syncthreads();

    const float* base = af + (size_t)b * LL * RNN + d0;
    float4 acc = {0.f, 0.f, 0.f, 0.f};
    #pragma unroll 4
    for (int l = 0; l < LL; ++l) {
        float wl = wsm[l];
        float4 v = *reinterpret_cast<const float4*>(base + (size_t)l * RNN);
        acc.x += wl * v.x; acc.y += wl * v.y; acc.z += wl * v.z; acc.w += wl * v.w;
    }
    *reinterpret_cast<float4*>(out + (size_t)b * RNN + d0) = acc;
}

extern "C" void kernel_launch(void* const* d_in, const int* in_sizes, int n_in,
                              void* d_out, int out_size, void* d_ws, size_t ws_size,
                              hipStream_t stream) {
    const float* h    = (const float*)d_in[0];   // [128,2048]
    const float* af   = (const float*)d_in[1];   // [128,196,2048]
    const float* iaf  = (const float*)d_in[2];   // [128,196,512]
    const float* w    = (const float*)d_in[3];   // [512,2048]
    const float* bias = (const float*)d_in[4];   // [512]
    const float* aw   = (const float*)d_in[5];   // [1,512]
    const float* ab   = (const float*)d_in[6];   // [1]
    float* out = (float*)d_out;

    float* ws_f    = (float*)d_ws;
    float* att_h   = ws_f;                       // 128*512
    float* scores  = ws_f + BB * AH;             // 128*196
    float* weight  = scores + BB * LL;           // 128*196

    k1_atth<<<dim3(16, 32), 256, 0, stream>>>(h, w, bias, att_h);

    int nwl = BB * LL;                           // 25088 waves
    k2_scores<<<(nwl + 3) / 4, 256, 0, stream>>>(iaf, att_h, aw, ab, scores);

    k3_softmax<<<BB, 256, 0, stream>>>(scores, weight);

    k4_out<<<dim3(4, BB), 128, 0, stream>>>(af, weight, out);
}

// Round 3
// 61.984 us; speedup vs baseline: 2.6511x; 1.0643x over previous
//
#include <hip/hip_runtime.h>

#define RNN 2048
#define AH  512
#define BB  128
#define LL  196

// ---------------- k1: att_h[b][a] = sum_k h[b][k]*w[a][k] + bias[a] ----------------
// Lanes run along K (coalesced w reads), shuffle-reduce at the end.
// Block: 256 threads = 4 waves; handles 4 b-rows x 32 a-cols.
__global__ __launch_bounds__(256) void k1_atth(const float* __restrict__ h,
                                               const float* __restrict__ w,
                                               const float* __restrict__ bias,
                                               float* __restrict__ att_h) {
    __shared__ float hs[4 * RNN];                 // 32 KB: 4 h rows
    const int tid  = threadIdx.x;
    const int wv   = tid >> 6, lane = tid & 63;
    const int b0   = blockIdx.y * 4;
    const int a0   = blockIdx.x * 32 + wv * 8;

    const float4* hg  = reinterpret_cast<const float4*>(h + (size_t)b0 * RNN);
    float4*       hs4 = reinterpret_cast<float4*>(hs);
    #pragma unroll
    for (int i = 0; i < 8; ++i) hs4[tid + i * 256] = hg[tid + i * 256];
    __syncthreads();

    float acc[8][4];
    #pragma unroll
    for (int ai = 0; ai < 8; ++ai)
        #pragma unroll
        for (int bl = 0; bl < 4; ++bl) acc[ai][bl] = 0.f;

    const float4* w4 = reinterpret_cast<const float4*>(w);
    #pragma unroll 1
    for (int i = 0; i < 8; ++i) {                 // k-chunks of 256 floats
        const int k4 = i * 64 + lane;
        float4 hv[4];
        #pragma unroll
        for (int bl = 0; bl < 4; ++bl) hv[bl] = hs4[bl * 512 + k4];
        #pragma unroll
        for (int ai = 0; ai < 8; ++ai) {
            float4 wvv = w4[(size_t)(a0 + ai) * 512 + k4];
            #pragma unroll
            for (int bl = 0; bl < 4; ++bl)
                acc[ai][bl] += wvv.x * hv[bl].x + wvv.y * hv[bl].y
                             + wvv.z * hv[bl].z + wvv.w * hv[bl].w;
        }
    }

    #pragma unroll
    for (int off = 32; off; off >>= 1)
        #pragma unroll
        for (int ai = 0; ai < 8; ++ai)
            #pragma unroll
            for (int bl = 0; bl < 4; ++bl)
                acc[ai][bl] += __shfl_xor(acc[ai][bl], off);

    if (lane == 0) {
        #pragma unroll
        for (int ai = 0; ai < 8; ++ai) {
            const float ba = bias[a0 + ai];
            #pragma unroll
            for (int bl = 0; bl < 4; ++bl)
                att_h[(b0 + bl) * AH + a0 + ai] = acc[ai][bl] + ba;
        }
    }
}

// ---------------- k2: scores[b][l] = sum_a tanh(iaf+att_h)*alpha_w + alpha_b -------
// one wave per (b,l); 8 waves per block.
__global__ __launch_bounds__(512) void k2_scores(const float* __restrict__ iaf,
                                                 const float* __restrict__ att_h,
                                                 const float* __restrict__ aw,
                                                 const float* __restrict__ ab,
                                                 float* __restrict__ scores) {
    const int wid  = blockIdx.x * 8 + (threadIdx.x >> 6);
    const int lane = threadIdx.x & 63;
    if (wid >= BB * LL) return;
    const int b = wid / LL, l = wid - b * LL;

    const float4* ir = reinterpret_cast<const float4*>(iaf + (size_t)(b * LL + l) * AH);
    const float4* hr = reinterpret_cast<const float4*>(att_h + (size_t)b * AH);
    const float4* ar = reinterpret_cast<const float4*>(aw);

    float s = 0.f;
    #pragma unroll
    for (int c = 0; c < 2; ++c) {
        int idx = lane + c * 64;
        float4 iv = ir[idx];
        float4 hv = hr[idx];
        float4 av = ar[idx];
        s += tanhf(iv.x + hv.x) * av.x
           + tanhf(iv.y + hv.y) * av.y
           + tanhf(iv.z + hv.z) * av.z
           + tanhf(iv.w + hv.w) * av.w;
    }
    #pragma unroll
    for (int off = 32; off; off >>= 1) s += __shfl_xor(s, off);
    if (lane == 0) scores[b * LL + l] = s + ab[0];
}

// ---------------- k4: fused softmax + out[b][d] = sum_l softmax(scores)[l]*af ------
// grid (4 d-chunks of 512, 128 b). 128 threads. Softmax recomputed per block (cheap).
__global__ __launch_bounds__(128) void k4_out(const float* __restrict__ af,
                                              const float* __restrict__ scores,
                                              float* __restrict__ out) {
    const int b  = blockIdx.y;
    const int t  = threadIdx.x;
    const int d0 = blockIdx.x * 512 + t * 4;

    __shared__ float wsm[LL];
    __shared__ float red[2][2];

    // softmax over scores[b][0..195] with 128 threads (each covers <=2)
    float v0 = (t < LL)       ? scores[b * LL + t]       : -1e30f;
    float v1 = (t + 128 < LL) ? scores[b * LL + t + 128] : -1e30f;

    float m = fmaxf(v0, v1);
    #pragma unroll
    for (int off = 32; off; off >>= 1) m = fmaxf(m, __shfl_xor(m, off));
    if ((t & 63) == 0) red[0][t >> 6] = m;
    __syncthreads();
    m = fmaxf(red[0][0], red[0][1]);

    float e0 = (t < LL)       ? __expf(v0 - m) : 0.f;
    float e1 = (t + 128 < LL) ? __expf(v1 - m) : 0.f;
    float s = e0 + e1;
    #pragma unroll
    for (int off = 32; off; off >>= 1) s += __shfl_xor(s, off);
    if ((t & 63) == 0) red[1][t >> 6] = s;
    __syncthreads();
    s = red[1][0] + red[1][1];
    const float inv = 1.f / s;

    if (t < LL)       wsm[t]       = e0 * inv;
    if (t + 128 < LL) wsm[t + 128] = e1 * inv;
    __syncthreads();

    // weighted sum: 196 iterations, unroll 7 (196 = 7*28) for deep in-flight loads
    const float* base = af + (size_t)b * LL * RNN + d0;
    float4 acc = {0.f, 0.f, 0.f, 0.f};
    #pragma unroll 7
    for (int l = 0; l < LL; ++l) {
        float wl = wsm[l];
        float4 v = *reinterpret_cast<const float4*>(base + (size_t)l * RNN);
        acc.x += wl * v.x; acc.y += wl * v.y; acc.z += wl * v.z; acc.w += wl * v.w;
    }
    *reinterpret_cast<float4*>(out + (size_t)b * RNN + d0) = acc;
}

extern "C" void kernel_launch(void* const* d_in, const int* in_sizes, int n_in,
                              void* d_out, int out_size, void* d_ws, size_t ws_size,
                              hipStream_t stream) {
    const float* h    = (const float*)d_in[0];   // [128,2048]
    const float* af   = (const float*)d_in[1];   // [128,196,2048]
    const float* iaf  = (const float*)d_in[2];   // [128,196,512]
    const float* w    = (const float*)d_in[3];   // [512,2048]
    const float* bias = (const float*)d_in[4];   // [512]
    const float* aw   = (const float*)d_in[5];   // [1,512]
    const float* ab   = (const float*)d_in[6];   // [1]
    float* out = (float*)d_out;

    float* ws_f    = (float*)d_ws;
    float* att_h   = ws_f;                       // 128*512
    float* scores  = ws_f + BB * AH;             // 128*196

    k1_atth<<<dim3(16, 32), 256, 0, stream>>>(h, w, bias, att_h);

    int nwl = BB * LL;                           // 25088 waves
    k2_scores<<<(nwl + 7) / 8, 512, 0, stream>>>(iaf, att_h, aw, ab, scores);

    k4_out<<<dim3(4, BB), 128, 0, stream>>>(af, scores, out);
}

// Round 4
// 61.314 us; speedup vs baseline: 2.6801x; 1.0109x over previous
//
#include <hip/hip_runtime.h>

#define RNN 2048
#define AH  512
#define BB  128
#define LL  196

// ---------------- k1: att_h[b][a] = sum_k h[b][k]*w[a][k] + bias[a] ----------------
// Lanes run along K (coalesced w reads), shuffle-reduce at the end.
__global__ __launch_bounds__(256) void k1_atth(const float* __restrict__ h,
                                               const float* __restrict__ w,
                                               const float* __restrict__ bias,
                                               float* __restrict__ att_h) {
    __shared__ float hs[4 * RNN];                 // 32 KB: 4 h rows
    const int tid  = threadIdx.x;
    const int wv   = tid >> 6, lane = tid & 63;
    const int b0   = blockIdx.y * 4;
    const int a0   = blockIdx.x * 32 + wv * 8;

    const float4* hg  = reinterpret_cast<const float4*>(h + (size_t)b0 * RNN);
    float4*       hs4 = reinterpret_cast<float4*>(hs);
    #pragma unroll
    for (int i = 0; i < 8; ++i) hs4[tid + i * 256] = hg[tid + i * 256];
    __syncthreads();

    float acc[8][4];
    #pragma unroll
    for (int ai = 0; ai < 8; ++ai)
        #pragma unroll
        for (int bl = 0; bl < 4; ++bl) acc[ai][bl] = 0.f;

    const float4* w4 = reinterpret_cast<const float4*>(w);
    #pragma unroll 1
    for (int i = 0; i < 8; ++i) {                 // k-chunks of 256 floats
        const int k4 = i * 64 + lane;
        float4 hv[4];
        #pragma unroll
        for (int bl = 0; bl < 4; ++bl) hv[bl] = hs4[bl * 512 + k4];
        #pragma unroll
        for (int ai = 0; ai < 8; ++ai) {
            float4 wvv = w4[(size_t)(a0 + ai) * 512 + k4];
            #pragma unroll
            for (int bl = 0; bl < 4; ++bl)
                acc[ai][bl] += wvv.x * hv[bl].x + wvv.y * hv[bl].y
                             + wvv.z * hv[bl].z + wvv.w * hv[bl].w;
        }
    }

    #pragma unroll
    for (int off = 32; off; off >>= 1)
        #pragma unroll
        for (int ai = 0; ai < 8; ++ai)
            #pragma unroll
            for (int bl = 0; bl < 4; ++bl)
                acc[ai][bl] += __shfl_xor(acc[ai][bl], off);

    if (lane == 0) {
        #pragma unroll
        for (int ai = 0; ai < 8; ++ai) {
            const float ba = bias[a0 + ai];
            #pragma unroll
            for (int bl = 0; bl < 4; ++bl)
                att_h[(b0 + bl) * AH + a0 + ai] = acc[ai][bl] + ba;
        }
    }
}

// ---------------- k2: scores[b][l] = sum_a tanh(iaf+att_h)*alpha_w + alpha_b -------
// one wave per (b,l); 8 waves per block.
__global__ __launch_bounds__(512) void k2_scores(const float* __restrict__ iaf,
                                                 const float* __restrict__ att_h,
                                                 const float* __restrict__ aw,
                                                 const float* __restrict__ ab,
                                                 float* __restrict__ scores) {
    const int wid  = blockIdx.x * 8 + (threadIdx.x >> 6);
    const int lane = threadIdx.x & 63;
    if (wid >= BB * LL) return;
    const int b = wid / LL, l = wid - b * LL;

    const float4* ir = reinterpret_cast<const float4*>(iaf + (size_t)(b * LL + l) * AH);
    const float4* hr = reinterpret_cast<const float4*>(att_h + (size_t)b * AH);
    const float4* ar = reinterpret_cast<const float4*>(aw);

    float s = 0.f;
    #pragma unroll
    for (int c = 0; c < 2; ++c) {
        int idx = lane + c * 64;
        float4 iv = ir[idx];
        float4 hv = hr[idx];
        float4 av = ar[idx];
        s += tanhf(iv.x + hv.x) * av.x
           + tanhf(iv.y + hv.y) * av.y
           + tanhf(iv.z + hv.z) * av.z
           + tanhf(iv.w + hv.w) * av.w;
    }
    #pragma unroll
    for (int off = 32; off; off >>= 1) s += __shfl_xor(s, off);
    if (lane == 0) scores[b * LL + l] = s + ab[0];
}

// ---------------- k4: fused softmax + out[b][d] = sum_l softmax(scores)[l]*af ------
// grid (4 d-chunks of 512, 128 b), 512 threads = 4 l-groups x 128 threads.
// Each l-group streams 49 of the 196 rows; cross-group reduce in LDS.
// 4096 waves total -> 16 waves/CU (vs 4 before): TLP to hide HBM latency.
__global__ __launch_bounds__(512) void k4_out(const float* __restrict__ af,
                                              const float* __restrict__ scores,
                                              float* __restrict__ out) {
    const int b  = blockIdx.y;
    const int t  = threadIdx.x;
    const int lg = t >> 7;            // l-group 0..3
    const int tt = t & 127;           // thread within group
    const int d0 = blockIdx.x * 512 + tt * 4;

    __shared__ float  wsm[LL];
    __shared__ float  red[8];
    __shared__ float4 p4[4][128];

    // softmax over scores[b][0..195] with 512 threads (8 waves)
    float v0 = (t < LL) ? scores[b * LL + t] : -1e30f;
    float m = v0;
    #pragma unroll
    for (int off = 32; off; off >>= 1) m = fmaxf(m, __shfl_xor(m, off));
    if ((t & 63) == 0) red[t >> 6] = m;
    __syncthreads();
    m = fmaxf(fmaxf(fmaxf(red[0], red[1]), fmaxf(red[2], red[3])),
              fmaxf(fmaxf(red[4], red[5]), fmaxf(red[6], red[7])));
    __syncthreads();

    float e0 = (t < LL) ? __expf(v0 - m) : 0.f;
    float s = e0;
    #pragma unroll
    for (int off = 32; off; off >>= 1) s += __shfl_xor(s, off);
    if ((t & 63) == 0) red[t >> 6] = s;
    __syncthreads();
    s = red[0] + red[1] + red[2] + red[3] + red[4] + red[5] + red[6] + red[7];
    const float inv = 1.f / s;
    if (t < LL) wsm[t] = e0 * inv;
    __syncthreads();

    // weighted partial sum over this group's 49 rows (49 = 7*7, unroll 7)
    const float* base = af + (size_t)b * LL * RNN + d0 + (size_t)(lg * 49) * RNN;
    float4 acc = {0.f, 0.f, 0.f, 0.f};
    #pragma unroll 7
    for (int i = 0; i < 49; ++i) {
        float wl = wsm[lg * 49 + i];
        float4 v = *reinterpret_cast<const float4*>(base + (size_t)i * RNN);
        acc.x += wl * v.x; acc.y += wl * v.y; acc.z += wl * v.z; acc.w += wl * v.w;
    }
    p4[lg][tt] = acc;
    __syncthreads();

    if (lg == 0) {
        float4 a0 = p4[0][tt], a1 = p4[1][tt], a2 = p4[2][tt], a3 = p4[3][tt];
        float4 r;
        r.x = (a0.x + a1.x) + (a2.x + a3.x);
        r.y = (a0.y + a1.y) + (a2.y + a3.y);
        r.z = (a0.z + a1.z) + (a2.z + a3.z);
        r.w = (a0.w + a1.w) + (a2.w + a3.w);
        *reinterpret_cast<float4*>(out + (size_t)b * RNN + d0) = r;
    }
}

extern "C" void kernel_launch(void* const* d_in, const int* in_sizes, int n_in,
                              void* d_out, int out_size, void* d_ws, size_t ws_size,
                              hipStream_t stream) {
    const float* h    = (const float*)d_in[0];   // [128,2048]
    const float* af   = (const float*)d_in[1];   // [128,196,2048]
    const float* iaf  = (const float*)d_in[2];   // [128,196,512]
    const float* w    = (const float*)d_in[3];   // [512,2048]
    const float* bias = (const float*)d_in[4];   // [512]
    const float* aw   = (const float*)d_in[5];   // [1,512]
    const float* ab   = (const float*)d_in[6];   // [1]
    float* out = (float*)d_out;

    float* ws_f    = (float*)d_ws;
    float* att_h   = ws_f;                       // 128*512
    float* scores  = ws_f + BB * AH;             // 128*196

    k1_atth<<<dim3(16, 32), 256, 0, stream>>>(h, w, bias, att_h);

    int nwl = BB * LL;                           // 25088 waves
    k2_scores<<<(nwl + 7) / 8, 512, 0, stream>>>(iaf, att_h, aw, ab, scores);

    k4_out<<<dim3(4, BB), 512, 0, stream>>>(af, scores, out);
}